// Round 2
// baseline (65.188 us; speedup 1.0000x reference)
//
#include <hip/hip_runtime.h>
#include <math.h>

#define NPART 2048
#define MSE_THREADS 256
#define MSE_UNROLL 10
#define B 64
#define N 54
#define E 54
#define C 5
#define LOG_CLAMP (-100.0f)

// ---------------- Kernel 1: big MSE partial reduction ----------------
// Geometry is fixed by the problem: n4 = 64*20*128*128/4 = 5,242,880
// = NPART * MSE_THREADS * MSE_UNROLL exactly. Compile-time trip count
// lets the compiler hoist all loads -> ~20 loads in flight per wave.
__global__ __launch_bounds__(MSE_THREADS) void k_mse_partial(const float* __restrict__ pred,
                                                             const float* __restrict__ ref,
                                                             float* __restrict__ part, int n4) {
    const float4* __restrict__ p4 = (const float4*)pred;
    const float4* __restrict__ r4 = (const float4*)ref;
    const int stride = NPART * MSE_THREADS;
    int idx = blockIdx.x * MSE_THREADS + threadIdx.x;
    float acc = 0.0f;

    if (n4 == stride * MSE_UNROLL) {
        // fast path: fully unrolled, loads batched for MLP
        float4 a[MSE_UNROLL], b[MSE_UNROLL];
        #pragma unroll
        for (int u = 0; u < MSE_UNROLL; u++) a[u] = p4[idx + u * stride];
        #pragma unroll
        for (int u = 0; u < MSE_UNROLL; u++) b[u] = r4[idx + u * stride];
        #pragma unroll
        for (int u = 0; u < MSE_UNROLL; u++) {
            float d0 = a[u].x - b[u].x, d1 = a[u].y - b[u].y;
            float d2 = a[u].z - b[u].z, d3 = a[u].w - b[u].w;
            acc = fmaf(d0, d0, acc);
            acc = fmaf(d1, d1, acc);
            acc = fmaf(d2, d2, acc);
            acc = fmaf(d3, d3, acc);
        }
    } else {
        // generic fallback
        for (int i = idx; i < n4; i += stride) {
            float4 a = p4[i];
            float4 b = r4[i];
            float d0 = a.x - b.x, d1 = a.y - b.y, d2 = a.z - b.z, d3 = a.w - b.w;
            acc = fmaf(d0, d0, acc);
            acc = fmaf(d1, d1, acc);
            acc = fmaf(d2, d2, acc);
            acc = fmaf(d3, d3, acc);
        }
    }

    #pragma unroll
    for (int off = 32; off > 0; off >>= 1) acc += __shfl_down(acc, off, 64);
    __shared__ float s[MSE_THREADS / 64];
    int lane = threadIdx.x & 63;
    int w = threadIdx.x >> 6;
    if (lane == 0) s[w] = acc;
    __syncthreads();
    if (threadIdx.x == 0) {
        float t = 0.0f;
        #pragma unroll
        for (int i = 0; i < MSE_THREADS / 64; i++) t += s[i];
        part[blockIdx.x] = t;
    }
}

// ---------------- Kernel 2: fused per-batch losses + finalize ----------------
// One block, 4 waves. Wave w handles batches w, w+4, ... (argmin + CE + BCE),
// then all 256 threads reduce the NPART partials, thread 0 combines.
__global__ __launch_bounds__(256) void k_final_fused(const float* __restrict__ part,
                                                     const float* __restrict__ pred_nodes,
                                                     const float* __restrict__ pred_edges,
                                                     const float* __restrict__ ref_nodes,
                                                     const float* __restrict__ ref_edges,
                                                     const int* __restrict__ ref_term,
                                                     float* __restrict__ out,
                                                     float inv_total) {
    int t = threadIdx.x;
    int lane = t & 63;
    int w = t >> 6;

    float csum = 0.0f, esum = 0.0f;
    for (int b = w; b < B; b += 4) {
        const float* pn = pred_nodes + b * (3 + C);
        float px = pn[0], py = pn[1], pz = pn[2];

        float d2 = 1e30f;
        int mi = lane;
        if (lane < N) {
            const float* rn = ref_nodes + ((long)b * N + lane) * 4;
            float dx = rn[0] - px, dy = rn[1] - py, dz = rn[2] - pz;
            d2 = dx * dx + dy * dy + dz * dz;
        }
        #pragma unroll
        for (int off = 32; off > 0; off >>= 1) {
            float od = __shfl_down(d2, off, 64);
            int oi = __shfl_down(mi, off, 64);
            if (od < d2 || (od == d2 && oi < mi)) { d2 = od; mi = oi; }
        }
        mi = __shfl(mi, 0, 64); // broadcast argmin (first-index tie-break)

        // class CE (uniform across lanes, cheap)
        int tgt = (int)ref_nodes[((long)b * N + mi) * 4 + 3];
        const float* logits = pn + 3;
        float m = logits[0];
        #pragma unroll
        for (int c = 1; c < C; c++) m = fmaxf(m, logits[c]);
        float se = 0.0f;
        #pragma unroll
        for (int c = 0; c < C; c++) se += __expf(logits[c] - m);
        float ce = logf(se) + m - logits[tgt];

        // edge BCE: lane handles edge `lane`
        float term = 0.0f;
        if (lane < E) {
            float sel = ref_edges[((long)b * N + mi) * E + lane];
            float p = pred_edges[b * E + lane];
            float lp = fmaxf(logf(p), LOG_CLAMP);
            float l1mp = fmaxf(log1pf(-p), LOG_CLAMP);
            term = -(sel * lp + (1.0f - sel) * l1mp);
        }
        #pragma unroll
        for (int off = 32; off > 0; off >>= 1) term += __shfl_down(term, off, 64);

        if (lane == 0) {
            float active = (ref_term[b] == 0) ? 1.0f : 0.0f;
            float ne = active * (term / (float)E);
            if (isnan(ne)) ne = 0.0f;
            csum += active * ce;
            esum += ne;
            out[1 + b] = (float)mi;
        }
    }

    __shared__ float s_c[4], s_e[4], s_p[4];
    if (lane == 0) { s_c[w] = csum; s_e[w] = esum; }

    // reduce the MSE partials with all 256 threads
    float acc = 0.0f;
    for (int i = t; i < NPART; i += 256) acc += part[i];
    #pragma unroll
    for (int off = 32; off > 0; off >>= 1) acc += __shfl_down(acc, off, 64);
    if (lane == 0) s_p[w] = acc;
    __syncthreads();

    if (t == 0) {
        float mse = (s_p[0] + s_p[1] + s_p[2] + s_p[3]) * inv_total;
        float cs = s_c[0] + s_c[1] + s_c[2] + s_c[3];
        float es = s_e[0] + s_e[1] + s_e[2] + s_e[3];
        out[0] = mse + (cs + es) * (1.0f / (float)B);
    }
}

extern "C" void kernel_launch(void* const* d_in, const int* in_sizes, int n_in,
                              void* d_out, int out_size, void* d_ws, size_t ws_size,
                              hipStream_t stream) {
    const float* pred_nodes = (const float*)d_in[0];
    const float* pred_edges = (const float*)d_in[1];
    const float* pred_dist  = (const float*)d_in[2];
    const float* ref_nodes  = (const float*)d_in[3];
    const float* ref_edges  = (const float*)d_in[4];
    const int*   ref_term   = (const int*)d_in[5];
    const float* ref_dist   = (const float*)d_in[6];

    float* out = (float*)d_out;   // [0] = loss, [1..64] = min_inds (as float)
    float* part = (float*)d_ws;   // NPART partials

    int n_dist = in_sizes[2];     // 64*20*128*128 = 20971520
    int n4 = n_dist / 4;

    k_mse_partial<<<NPART, MSE_THREADS, 0, stream>>>(pred_dist, ref_dist, part, n4);
    k_final_fused<<<1, 256, 0, stream>>>(part, pred_nodes, pred_edges, ref_nodes,
                                         ref_edges, ref_term, out,
                                         1.0f / (float)n_dist);
}

// Round 3
// 36.988 us; speedup vs baseline: 1.7624x; 1.7624x over previous
//
#include <hip/hip_runtime.h>
#include <math.h>

#define NPART 2048
#define MSE_THREADS 256
#define MSE_UNROLL 10
#define B 64
#define N 54
#define E 54
#define C 5
#define LOG_CLAMP (-100.0f)

// ---------------- Kernel 1: fused MSE partials + per-batch losses ----------------
// Blocks [0, NPART): grid-strided MSE partial reduction over pred/ref dist.
// Blocks [NPART, NPART+B): per-batch argmin + CE + BCE (one wave active).
__global__ __launch_bounds__(MSE_THREADS) void k_main(const float* __restrict__ pred_dist,
                                                      const float* __restrict__ ref_dist,
                                                      const float* __restrict__ pred_nodes,
                                                      const float* __restrict__ pred_edges,
                                                      const float* __restrict__ ref_nodes,
                                                      const float* __restrict__ ref_edges,
                                                      const int* __restrict__ ref_term,
                                                      float* __restrict__ part,   // [NPART]
                                                      float* __restrict__ nll,    // [B]
                                                      float* __restrict__ out,    // [0]=loss,[1..B]=min_inds
                                                      int n4) {
    if (blockIdx.x < NPART) {
        // ---- MSE streaming path ----
        const float4* __restrict__ p4 = (const float4*)pred_dist;
        const float4* __restrict__ r4 = (const float4*)ref_dist;
        const int stride = NPART * MSE_THREADS;
        int idx = blockIdx.x * MSE_THREADS + threadIdx.x;
        float acc = 0.0f;

        if (n4 == stride * MSE_UNROLL) {
            float4 a[MSE_UNROLL], b[MSE_UNROLL];
            #pragma unroll
            for (int u = 0; u < MSE_UNROLL; u++) a[u] = p4[idx + u * stride];
            #pragma unroll
            for (int u = 0; u < MSE_UNROLL; u++) b[u] = r4[idx + u * stride];
            #pragma unroll
            for (int u = 0; u < MSE_UNROLL; u++) {
                float d0 = a[u].x - b[u].x, d1 = a[u].y - b[u].y;
                float d2 = a[u].z - b[u].z, d3 = a[u].w - b[u].w;
                acc = fmaf(d0, d0, acc);
                acc = fmaf(d1, d1, acc);
                acc = fmaf(d2, d2, acc);
                acc = fmaf(d3, d3, acc);
            }
        } else {
            for (int i = idx; i < n4; i += stride) {
                float4 a = p4[i];
                float4 b = r4[i];
                float d0 = a.x - b.x, d1 = a.y - b.y, d2 = a.z - b.z, d3 = a.w - b.w;
                acc = fmaf(d0, d0, acc);
                acc = fmaf(d1, d1, acc);
                acc = fmaf(d2, d2, acc);
                acc = fmaf(d3, d3, acc);
            }
        }

        #pragma unroll
        for (int off = 32; off > 0; off >>= 1) acc += __shfl_down(acc, off, 64);
        __shared__ float s[MSE_THREADS / 64];
        int lane = threadIdx.x & 63;
        int w = threadIdx.x >> 6;
        if (lane == 0) s[w] = acc;
        __syncthreads();
        if (threadIdx.x == 0) {
            float t = 0.0f;
            #pragma unroll
            for (int i = 0; i < MSE_THREADS / 64; i++) t += s[i];
            part[blockIdx.x] = t;
        }
    } else {
        // ---- per-batch path: one wave does batch b ----
        int b = blockIdx.x - NPART;
        int t = threadIdx.x;
        if (t >= 64) return;
        const float* pn = pred_nodes + b * (3 + C);
        float px = pn[0], py = pn[1], pz = pn[2];

        float d2 = 1e30f;
        int mi = t;
        if (t < N) {
            const float* rn = ref_nodes + ((long)b * N + t) * 4;
            float dx = rn[0] - px, dy = rn[1] - py, dz = rn[2] - pz;
            d2 = dx * dx + dy * dy + dz * dz;
        }
        #pragma unroll
        for (int off = 32; off > 0; off >>= 1) {
            float od = __shfl_down(d2, off, 64);
            int oi = __shfl_down(mi, off, 64);
            if (od < d2 || (od == d2 && oi < mi)) { d2 = od; mi = oi; }
        }
        mi = __shfl(mi, 0, 64); // broadcast argmin (first-index tie-break)

        // class CE (wave-uniform, cheap)
        int tgt = (int)ref_nodes[((long)b * N + mi) * 4 + 3];
        const float* logits = pn + 3;
        float m = logits[0];
        #pragma unroll
        for (int c = 1; c < C; c++) m = fmaxf(m, logits[c]);
        float se = 0.0f;
        #pragma unroll
        for (int c = 0; c < C; c++) se += __expf(logits[c] - m);
        float ce = logf(se) + m - logits[tgt];

        // edge BCE: lane t handles edge t
        float term = 0.0f;
        if (t < E) {
            float sel = ref_edges[((long)b * N + mi) * E + t];
            float p = pred_edges[b * E + t];
            float lp = fmaxf(logf(p), LOG_CLAMP);
            float l1mp = fmaxf(log1pf(-p), LOG_CLAMP);
            term = -(sel * lp + (1.0f - sel) * l1mp);
        }
        #pragma unroll
        for (int off = 32; off > 0; off >>= 1) term += __shfl_down(term, off, 64);

        if (t == 0) {
            float active = (ref_term[b] == 0) ? 1.0f : 0.0f;
            float ne = active * (term / (float)E);
            if (isnan(ne)) ne = 0.0f;
            nll[b] = active * ce + ne;
            out[1 + b] = (float)mi;
        }
    }
}

// ---------------- Kernel 2: finalize ----------------
__global__ __launch_bounds__(256) void k_final(const float* __restrict__ part,
                                               const float* __restrict__ nll,
                                               float* __restrict__ out,
                                               float inv_total) {
    int t = threadIdx.x;
    int lane = t & 63;
    int w = t >> 6;
    float acc = 0.0f;
    for (int i = t; i < NPART; i += 256) acc += part[i];
    float nacc = (t < B) ? nll[t] : 0.0f;
    #pragma unroll
    for (int off = 32; off > 0; off >>= 1) {
        acc += __shfl_down(acc, off, 64);
        nacc += __shfl_down(nacc, off, 64);
    }
    __shared__ float s_p[4], s_n[4];
    if (lane == 0) { s_p[w] = acc; s_n[w] = nacc; }
    __syncthreads();
    if (t == 0) {
        float mse = (s_p[0] + s_p[1] + s_p[2] + s_p[3]) * inv_total;
        float ns = s_n[0] + s_n[1] + s_n[2] + s_n[3];
        out[0] = mse + ns * (1.0f / (float)B);
    }
}

extern "C" void kernel_launch(void* const* d_in, const int* in_sizes, int n_in,
                              void* d_out, int out_size, void* d_ws, size_t ws_size,
                              hipStream_t stream) {
    const float* pred_nodes = (const float*)d_in[0];
    const float* pred_edges = (const float*)d_in[1];
    const float* pred_dist  = (const float*)d_in[2];
    const float* ref_nodes  = (const float*)d_in[3];
    const float* ref_edges  = (const float*)d_in[4];
    const int*   ref_term   = (const int*)d_in[5];
    const float* ref_dist   = (const float*)d_in[6];

    float* out  = (float*)d_out;      // [0]=loss, [1..64]=min_inds (as float)
    float* part = (float*)d_ws;       // NPART partials
    float* nll  = part + NPART;       // B combined per-batch losses

    int n_dist = in_sizes[2];         // 64*20*128*128 = 20971520
    int n4 = n_dist / 4;

    k_main<<<NPART + B, MSE_THREADS, 0, stream>>>(pred_dist, ref_dist, pred_nodes,
                                                  pred_edges, ref_nodes, ref_edges,
                                                  ref_term, part, nll, out, n4);
    k_final<<<1, 256, 0, stream>>>(part, nll, out, 1.0f / (float)n_dist);
}